// Round 13
// baseline (207.269 us; speedup 1.0000x reference)
//
#include <hip/hip_runtime.h>
#include <hip/hip_bf16.h>

#define NN 7936
#define EE 63488
#define CIN 5
#define WW 64
#define KK 8
#define H1C 64
#define H2C 16
#define T1 57            // 64-8+1
#define T2 50            // 57-8+1
#define FT (T1*H2C)      // 912 elems per node for xt (f16)
#define CAP 64           // fixed bucket capacity (P(deg>=64) ~ 1e-35)
#define GSTR 24          // gs row stride in halves (48 B: 16-B aligned rows)

typedef _Float16 half8 __attribute__((ext_vector_type(8)));
typedef _Float16 half4v __attribute__((ext_vector_type(4)));
typedef float f32x4 __attribute__((ext_vector_type(4)));

// ---------------------------------------------------------------------------
// Per-block int64-layout detection: first wave checks high words of the first
// 32 edge indices, ballot, LDS broadcast. ~32 L2-hot ints per block.
__device__ __forceinline__ int block_flag(const int* __restrict__ ei,
                                          int* sflag) {
    if (threadIdx.x < 64) {
        int bad = (threadIdx.x < 32) ? (ei[2 * threadIdx.x + 1] != 0) : 0;
        unsigned long long b = __ballot(bad);
        if (threadIdx.x == 0) *sflag = (b == 0ULL) ? 1 : 0;
    }
    __syncthreads();
    return *sflag;
}

__device__ __forceinline__ int load_row(const int* ei, int f, int e) {
    return f ? ei[2 * e] : ei[e];
}
__device__ __forceinline__ int load_col(const int* ei, int f, int e) {
    return f ? ei[2 * (EE + e)] : ei[EE + e];
}

// ---------------------------------------------------------------------------
// k_init: blocks 0..61 zero deg|cnt (contiguous 2*NN words, 62*256 = 15872
// exactly); blocks 62..125 do conv2 B-frag prep (16384 elems). w1p/wgp prep
// is GONE — conv1 now loads Wc1/Wg directly with the permutation folded into
// its addresses (the sigma rows are 8-consecutive-float runs -> two L1-hot
// float4 loads per fragment).
// w2p k-order: element e of a B-frag is (ci = g*4 + (e&3), tap = 2*s+(e>>2))
// — taps grouped in halves so the gc2 A-frag is a plain concat of two 8-B
// LDS rows. MFMA sums over k, so any A/B-consistent k-permutation is valid.
__global__ void k_init(float* __restrict__ deg,
                       const float* __restrict__ Wc2, _Float16* __restrict__ w2p) {
    int b = blockIdx.x;
    if (b < 62) {
        // deg and cnt are contiguous in ws: zero both as one word range
        ((int*)deg)[b * 256 + threadIdx.x] = 0;
        return;
    }
    int i = (b - 62) * 256 + threadIdx.x;
    // conv2 B-frags: slot=(s*4+lg)*128+nt*16+c, elem e
    int e = i & 7;
    int slot = i >> 3;
    int c  = slot & 15;
    int nt = (slot >> 4) & 7;
    int g  = (slot >> 7) & 3;
    int s  = (slot >> 9) & 3;
    int ci = g * 4 + (e & 3);
    w2p[i] = (_Float16)Wc2[(nt * 16 + c) * 128 + ci * 8 + 2 * s + (e >> 2)];
}

// ---------------------------------------------------------------------------
// Merged kernel: blocks [0, NN/4) run conv1 (register-resident, wave = node);
// blocks [NN/4, NN/4+EE/256) run the edge bucket-fill into FIXED-CAPACITY
// buckets em[c*64+pos], storing RAW (src, ew) and accumulating deg[c] here
// (the dinv[src] fold lives in gc2's prefetch path).
__global__ __launch_bounds__(256, 3) void k_conv1_fill(
        const float* __restrict__ x, const float* __restrict__ Wc1,
        const float* __restrict__ b1, const float* __restrict__ Wg,
        _Float16* __restrict__ xt,
        const int* __restrict__ ei,
        const float* __restrict__ ew, float* __restrict__ deg,
        int* __restrict__ cnt, int2* __restrict__ em) {
    if (blockIdx.x >= NN / 4) {
        // ---- bucket fill: em[c*64+pos] = (src, ew); deg[c] += ew ----
        __shared__ int sflag;
        int f = block_flag(ei, &sflag);
        int e = (blockIdx.x - NN / 4) * 256 + threadIdx.x;
        if (e < EE) {
            int c = load_col(ei, f, e);
            int r = load_row(ei, f, e);
            float wv = ew[e];
            int pos = atomicAdd(&cnt[c], 1);
            atomicAdd(&deg[c], wv);
            if (pos < CAP)
                em[(c << 6) + pos] = make_int2(r, __float_as_int(wv));
        }
        return;
    }
    // ---- conv1, fully register-resident (zero LDS, zero barriers) ----
    int tid = threadIdx.x;
    int w = tid >> 6, lane = tid & 63;
    int lc = lane & 15, lg = lane >> 4;
    int n = blockIdx.x * 4 + w;
    const float* xg = x + (size_t)n * (CIN * WW);

    // A-frags direct from Wc1 with sigma permutation folded into addresses:
    // m = mt*16+lc -> sig = (mt>>2)*64 + 32*((mt&3)>>1) + 8*(lc>>2)
    //                 + 4*((mt&3)&1) + (lc&3); row run = Wc1[sig*40 + ci*8 ..]
    half8 av[2][8];
#pragma unroll
    for (int s = 0; s < 2; ++s) {
        int ci = s * 4 + lg;
#pragma unroll
        for (int mt = 0; mt < 8; ++mt) {
            half8 v = (half8)(_Float16)0.0f;
            if (ci < CIN) {
                int mb = mt & 3;
                int sig = (mt >> 2) * 64 + 32 * (mb >> 1) + 8 * (lc >> 2) +
                          4 * (mb & 1) + (lc & 3);
                const float* wr = Wc1 + sig * (CIN * KK) + ci * KK;
                float4 fA = *(const float4*)(wr);
                float4 fB = *(const float4*)(wr + 4);
                v[0] = (_Float16)fA.x; v[1] = (_Float16)fA.y;
                v[2] = (_Float16)fA.z; v[3] = (_Float16)fA.w;
                v[4] = (_Float16)fB.x; v[5] = (_Float16)fB.y;
                v[6] = (_Float16)fB.z; v[7] = (_Float16)fB.w;
            }
            av[s][mt] = v;
        }
    }
    // GEMM2 B-frags direct from Wg: bw[s2][e] = Wg[(s2*32+lg*8+e)*16 + lc]
    half8 bw[2];
#pragma unroll
    for (int s2 = 0; s2 < 2; ++s2) {
        half8 v;
#pragma unroll
        for (int e = 0; e < 8; ++e)
            v[e] = (_Float16)Wg[(s2 * 32 + lg * 8 + e) * H2C + lc];
        bw[s2] = v;
    }

    const float* xr0 = xg + (size_t)lg * WW;
    const float* xr1 = xg + (size_t)(4 + lg) * WW;
    bool cok1 = (4 + lg) < CIN;

    f32x4 acc2[4];
#pragma unroll
    for (int mt2 = 0; mt2 < 4; ++mt2) acc2[mt2] = (f32x4)0.0f;

#pragma unroll
    for (int nt = 0; nt < 4; ++nt) {
        int t = nt * 16 + lc;
        half8 bf0, bf1;
#pragma unroll
        for (int e = 0; e < 8; ++e) {
            int tp = t + e;
            bf0[e] = (_Float16)((tp < WW) ? xr0[tp] : 0.0f);
            bf1[e] = (_Float16)((cok1 && tp < WW) ? xr1[tp] : 0.0f);
        }
        f32x4 acc[8];
#pragma unroll
        for (int mt = 0; mt < 8; ++mt) acc[mt] = (f32x4)0.0f;
#pragma unroll
        for (int mt = 0; mt < 8; ++mt)
            acc[mt] = __builtin_amdgcn_mfma_f32_16x16x32_f16(av[0][mt], bf0,
                                                             acc[mt], 0, 0, 0);
#pragma unroll
        for (int mt = 0; mt < 8; ++mt)
            acc[mt] = __builtin_amdgcn_mfma_f32_16x16x32_f16(av[1][mt], bf1,
                                                             acc[mt], 0, 0, 0);
        half4v h4[4];
#pragma unroll
        for (int mtp = 0; mtp < 4; ++mtp) {
            int cb = 32 * (mtp >> 1) + 8 * lg + 4 * (mtp & 1);
            float4 bP = *(const float4*)(b1 + cb);
            float4 bQ = *(const float4*)(b1 + 64 + cb);
            f32x4 P = acc[mtp];
            f32x4 Q = acc[mtp + 4];
            half4v hh;
            hh[0] = (_Float16)((P[0] + bP.x) * (1.0f / (1.0f + __expf(-(Q[0] + bQ.x)))));
            hh[1] = (_Float16)((P[1] + bP.y) * (1.0f / (1.0f + __expf(-(Q[1] + bQ.y)))));
            hh[2] = (_Float16)((P[2] + bP.z) * (1.0f / (1.0f + __expf(-(Q[2] + bQ.z)))));
            hh[3] = (_Float16)((P[3] + bP.w) * (1.0f / (1.0f + __expf(-(Q[3] + bQ.w)))));
            h4[mtp] = hh;
        }
#pragma unroll
        for (int s2 = 0; s2 < 2; ++s2) {
            half8 af = __builtin_shufflevector(h4[2 * s2], h4[2 * s2 + 1],
                                               0, 1, 2, 3, 4, 5, 6, 7);
            acc2[nt] = __builtin_amdgcn_mfma_f32_16x16x32_f16(af, bw[s2],
                                                              acc2[nt], 0, 0, 0);
        }
    }

    _Float16* xtn = xt + (size_t)n * FT;
#pragma unroll
    for (int mt2 = 0; mt2 < 4; ++mt2) {
#pragma unroll
        for (int j = 0; j < 4; ++j) {
            int t = mt2 * 16 + 4 * lg + j;
            if (t < T1) xtn[t * 16 + lc] = (_Float16)acc2[mt2][j];
        }
    }
}

// ---------------------------------------------------------------------------
// Fused gather + conv2, TWO WAVES PER NODE, now ONE NODE PER 128-THREAD BLOCK
// (occupancy probe: 9.2 KB LDS/block -> 16 blocks/CU = 32 waves, finer
// scheduling granularity than the 4-wave blocks which averaged only 36%
// occupancy). Gather loop is the r10-exact form (measured best, 65.2 µs):
// 1-deep row pipeline, act-masked loads, em/deg prefetched 2-deep with the
// rsqrt off the critical chain. r11 (2-deep ring) and r12 (unroll-2 +
// unconditional loads) were both neutral-to-worse — depth and ILP are not
// the wall; reverted.
// gs2 per-node [t][f] 48-B rows (b128 writes, b64 frag reads, k-order in
// w2p). One __syncthreads; each wave does 2 of 4 ntp quadrants; LDS-staged
// coalesced NONTEMPORAL stores (keeps write stream out of L2 -> xt stays
// resident). setprio(1) around the MFMA cluster (independent-wave kernel).
__global__ __launch_bounds__(128, 8) void k_gc2(
        const _Float16* __restrict__ xt, const float* __restrict__ deg,
        const int* __restrict__ cnt, const int2* __restrict__ em,
        const float* __restrict__ bg, const _Float16* __restrict__ w2p,
        const float* __restrict__ b2, float* __restrict__ out) {
    __shared__ __align__(16) _Float16 gs2[58 * GSTR];   // per node, 2784 B
    __shared__ __align__(16) float gout[2][16 * T2];    // per wave, 3200 B
    int tid = threadIdx.x;
    int h = tid >> 6, lane = tid & 63;
    int lc = lane & 15, lg = lane >> 4;
    int n = blockIdx.x;
    bool act = (h == 0) || (lane < 50);
    int idx = (h << 6) + lane;          // half8 index into a node row

    float dc = rsqrtf(deg[n] + 1.0f);
    float a[8];
    {
        const half8* xs = (const half8*)(xt + (size_t)n * FT);
        half8 u = (half8)(_Float16)0.0f;
        if (act) u = xs[idx];
#pragma unroll
        for (int j = 0; j < 8; ++j) a[j] = (float)u[j] * dc;   // self: x*dc
    }
    int beg = n << 6;
    int m = min(cnt[n], CAP);
    int2 rw0 = make_int2(0, 0), rw1 = make_int2(0, 0);
    float dg0 = 0.0f, dg1 = 0.0f;
    half8 c0 = (half8)(_Float16)0.0f;
    if (m > 0) {
        rw0 = em[beg];
        dg0 = deg[rw0.x];
        const half8* xr = (const half8*)(xt + (size_t)rw0.x * FT);
        if (act) c0 = xr[idx];
    }
    if (m > 1) { rw1 = em[beg + 1]; dg1 = deg[rw1.x]; }
    for (int i = 0; i < m; ++i) {
        float wv = __int_as_float(rw0.y) * rsqrtf(dg0 + 1.0f);
        half8 d0 = c0;
        int2 rwn = rw1;
        float dgn = dg1;
        if (i + 2 < m) { rwn = em[beg + i + 2]; dgn = deg[rwn.x]; }
        if (i + 1 < m) {
            const half8* xr = (const half8*)(xt + (size_t)rw1.x * FT);
            c0 = (half8)(_Float16)0.0f;
            if (act) c0 = xr[idx];
        }
        rw0 = rw1; dg0 = dg1; rw1 = rwn; dg1 = dgn;
#pragma unroll
        for (int j = 0; j < 8; ++j) a[j] += (float)d0[j] * wv;
    }

    // relu + bias -> gs2[t][f] (48-B rows). Lane owns t = idx>>1,
    // f = (lane&1)*8 .. +8. One b128 write per active lane.
    // Final feature = dc * (x*dc + sum) + bg, relu.
    {
        _Float16* g = gs2;
        int f0 = (lane & 1) * 8;
        int t0 = idx >> 1;
        float4 bgA = *(const float4*)(bg + f0);
        float4 bgB = *(const float4*)(bg + f0 + 4);
        float bv[8] = {bgA.x, bgA.y, bgA.z, bgA.w, bgB.x, bgB.y, bgB.z, bgB.w};
        half8 h0;
#pragma unroll
        for (int j = 0; j < 8; ++j)
            h0[j] = (_Float16)fmaxf(a[j] * dc + bv[j], 0.0f);
        if (act) *(half8*)(g + t0 * GSTR + f0) = h0;
    }
    __syncthreads();   // both halves' gs2 rows visible to both waves

    const _Float16* g = gs2;
    half8 af[4][4];
#pragma unroll
    for (int s = 0; s < 4; ++s)
#pragma unroll
        for (int mt = 0; mt < 4; ++mt) {
            int tb = mt * 16 + lc + 2 * s;
            half4v lo = *(const half4v*)(g + tb * GSTR + lg * 4);
            half4v hh = *(const half4v*)(g + (tb + 1) * GSTR + lg * 4);
            af[s][mt] = __builtin_shufflevector(lo, hh, 0, 1, 2, 3, 4, 5, 6, 7);
        }

    const half8* wsv = (const half8*)w2p;
    float* outn = out + (size_t)n * (H1C * T2);
    float* go = gout[h];
#pragma unroll
    for (int np2 = 0; np2 < 2; ++np2) {
        int ntp = (h << 1) + np2;
        f32x4 aP[4], aQ[4];
#pragma unroll
        for (int mt = 0; mt < 4; ++mt) { aP[mt] = (f32x4)0.0f; aQ[mt] = (f32x4)0.0f; }
        __builtin_amdgcn_s_setprio(1);
#pragma unroll
        for (int s = 0; s < 4; ++s) {
            half8 bP = wsv[(s * 4 + lg) * 128 + ntp * 16 + lc];
            half8 bQ = wsv[(s * 4 + lg) * 128 + (ntp + 4) * 16 + lc];
#pragma unroll
            for (int mt = 0; mt < 4; ++mt) {
                aP[mt] = __builtin_amdgcn_mfma_f32_16x16x32_f16(af[s][mt], bP,
                                                                aP[mt], 0, 0, 0);
                aQ[mt] = __builtin_amdgcn_mfma_f32_16x16x32_f16(af[s][mt], bQ,
                                                                aQ[mt], 0, 0, 0);
            }
        }
        __builtin_amdgcn_s_setprio(0);
        int c = ntp * 16 + lc;
        float bp = b2[c], bq = b2[64 + c];
        // stage [lc][t<50] into wave-private LDS (column-major rows of 50)
#pragma unroll
        for (int mt = 0; mt < 4; ++mt) {
#pragma unroll
            for (int e2 = 0; e2 < 4; ++e2) {
                int t = mt * 16 + lg * 4 + e2;
                if (t < T2) {
                    float vv = (aP[mt][e2] + bp) *
                               (1.0f / (1.0f + __expf(-(aQ[mt][e2] + bq))));
                    go[lc * T2 + t] = vv;
                }
            }
        }
        // coalesced nontemporal writeback: 800 floats = 3x1024B + 128B
        float* dst = outn + ntp * (16 * T2);
#pragma unroll
        for (int i = 0; i < 3; ++i) {
            f32x4 v = *(const f32x4*)(go + i * 256 + lane * 4);
            __builtin_nontemporal_store(v, (f32x4*)(dst + i * 256 + lane * 4));
        }
        if (lane < 8) {
            f32x4 v = *(const f32x4*)(go + 768 + lane * 4);
            __builtin_nontemporal_store(v, (f32x4*)(dst + 768 + lane * 4));
        }
    }
}

// ---------------------------------------------------------------------------
extern "C" void kernel_launch(void* const* d_in, const int* in_sizes, int n_in,
                              void* d_out, int out_size, void* d_ws, size_t ws_size,
                              hipStream_t stream) {
    const float* x   = (const float*)d_in[0];
    const int*   ei  = (const int*)d_in[1];
    const float* ea  = (const float*)d_in[2];
    const float* Wc1 = (const float*)d_in[4];
    const float* b1  = (const float*)d_in[5];
    const float* Wg  = (const float*)d_in[6];
    const float* bg  = (const float*)d_in[7];
    const float* Wc2 = (const float*)d_in[8];
    const float* b2  = (const float*)d_in[9];
    float* out = (float*)d_out;

    char* ws = (char*)d_ws;
    size_t off = 0;
    auto alloc = [&](size_t bytes) -> void* {
        void* p = ws + off;
        off += (bytes + 255) & ~(size_t)255;
        return p;
    };
    // deg | cnt contiguous -> k_init zeroes both as one 2*NN word range
    float*    deg = (float*)alloc((size_t)NN * 4);      // 31744
    int*      cnt = (int*)alloc((size_t)NN * 4);        // 31744
    int2*     em  = (int2*)alloc((size_t)NN * CAP * 8); // 4.06 MB fixed-cap
    _Float16* xt  = (_Float16*)alloc((size_t)NN * FT * 2);
    _Float16* w2p = (_Float16*)alloc((size_t)16384 * 2);
    (void)alloc(4096);                  // read-slack guard past xt/w2p
    (void)ws_size; (void)in_sizes; (void)n_in; (void)out_size;

    k_init<<<126, 256, 0, stream>>>(deg, Wc2, w2p);
    k_conv1_fill<<<NN / 4 + EE / 256, 256, 0, stream>>>(x, Wc1, b1, Wg, xt,
                                                        ei, ea, deg, cnt, em);
    k_gc2<<<NN, 128, 0, stream>>>(xt, deg, cnt, em, bg, w2p, b2, out);
}

// Round 14
// 102.420 us; speedup vs baseline: 2.0237x; 2.0237x over previous
//
#include <hip/hip_runtime.h>
#include <hip/hip_bf16.h>

#define NN 7936
#define EE 63488
#define CIN 5
#define WW 64
#define KK 8
#define H1C 64
#define H2C 16
#define T1 57            // 64-8+1
#define T2 50            // 57-8+1
#define FT (T1*H2C)      // 912 elems per node for xt (f16)
#define CAP 64           // fixed bucket capacity (P(deg>=64) ~ 1e-35)
#define GSTR 24          // gs row stride in halves (48 B: 16-B aligned rows)

typedef _Float16 half8 __attribute__((ext_vector_type(8)));
typedef _Float16 half4v __attribute__((ext_vector_type(4)));
typedef float f32x4 __attribute__((ext_vector_type(4)));

// ---------------------------------------------------------------------------
// Per-block int64-layout detection: first wave checks high words of the first
// 32 edge indices, ballot, LDS broadcast. ~32 L2-hot ints per block.
__device__ __forceinline__ int block_flag(const int* __restrict__ ei,
                                          int* sflag) {
    if (threadIdx.x < 64) {
        int bad = (threadIdx.x < 32) ? (ei[2 * threadIdx.x + 1] != 0) : 0;
        unsigned long long b = __ballot(bad);
        if (threadIdx.x == 0) *sflag = (b == 0ULL) ? 1 : 0;
    }
    __syncthreads();
    return *sflag;
}

__device__ __forceinline__ int load_row(const int* ei, int f, int e) {
    return f ? ei[2 * e] : ei[e];
}
__device__ __forceinline__ int load_col(const int* ei, int f, int e) {
    return f ? ei[2 * (EE + e)] : ei[EE + e];
}

// ---------------------------------------------------------------------------
// k_init: blocks 0..61 zero deg|cnt (contiguous 2*NN words, 62*256 = 15872
// exactly); blocks 62..125 do conv2 B-frag prep (16384 elems). conv1 loads
// Wc1/Wg directly (permutation folded into addresses).
// w2p k-order: element e of a B-frag is (ci = g*4 + (e&3), tap = 2*s+(e>>2))
// — taps grouped in halves so the gc2 A-frag is a plain concat of two 8-B
// LDS rows. MFMA sums over k, so any A/B-consistent k-permutation is valid.
__global__ void k_init(float* __restrict__ deg,
                       const float* __restrict__ Wc2, _Float16* __restrict__ w2p) {
    int b = blockIdx.x;
    if (b < 62) {
        // deg and cnt are contiguous in ws: zero both as one word range
        ((int*)deg)[b * 256 + threadIdx.x] = 0;
        return;
    }
    int i = (b - 62) * 256 + threadIdx.x;
    // conv2 B-frags: slot=(s*4+lg)*128+nt*16+c, elem e
    int e = i & 7;
    int slot = i >> 3;
    int c  = slot & 15;
    int nt = (slot >> 4) & 7;
    int g  = (slot >> 7) & 3;
    int s  = (slot >> 9) & 3;
    int ci = g * 4 + (e & 3);
    w2p[i] = (_Float16)Wc2[(nt * 16 + c) * 128 + ci * 8 + 2 * s + (e >> 2)];
}

// ---------------------------------------------------------------------------
// Merged kernel: blocks [0, NN/4) run conv1 (register-resident, wave = node);
// blocks [NN/4, NN/4+EE/256) run the edge bucket-fill into FIXED-CAPACITY
// buckets em[c*64+pos], storing RAW (src, ew) and accumulating deg[c] here
// (the dinv[src] fold lives in gc2's prefetch path).
__global__ __launch_bounds__(256, 3) void k_conv1_fill(
        const float* __restrict__ x, const float* __restrict__ Wc1,
        const float* __restrict__ b1, const float* __restrict__ Wg,
        _Float16* __restrict__ xt,
        const int* __restrict__ ei,
        const float* __restrict__ ew, float* __restrict__ deg,
        int* __restrict__ cnt, int2* __restrict__ em) {
    if (blockIdx.x >= NN / 4) {
        // ---- bucket fill: em[c*64+pos] = (src, ew); deg[c] += ew ----
        __shared__ int sflag;
        int f = block_flag(ei, &sflag);
        int e = (blockIdx.x - NN / 4) * 256 + threadIdx.x;
        if (e < EE) {
            int c = load_col(ei, f, e);
            int r = load_row(ei, f, e);
            float wv = ew[e];
            int pos = atomicAdd(&cnt[c], 1);
            atomicAdd(&deg[c], wv);
            if (pos < CAP)
                em[(c << 6) + pos] = make_int2(r, __float_as_int(wv));
        }
        return;
    }
    // ---- conv1, fully register-resident (zero LDS, zero barriers) ----
    int tid = threadIdx.x;
    int w = tid >> 6, lane = tid & 63;
    int lc = lane & 15, lg = lane >> 4;
    int n = blockIdx.x * 4 + w;
    const float* xg = x + (size_t)n * (CIN * WW);

    // A-frags direct from Wc1 with sigma permutation folded into addresses:
    // m = mt*16+lc -> sig = (mt>>2)*64 + 32*((mt&3)>>1) + 8*(lc>>2)
    //                 + 4*((mt&3)&1) + (lc&3); row run = Wc1[sig*40 + ci*8 ..]
    half8 av[2][8];
#pragma unroll
    for (int s = 0; s < 2; ++s) {
        int ci = s * 4 + lg;
#pragma unroll
        for (int mt = 0; mt < 8; ++mt) {
            half8 v = (half8)(_Float16)0.0f;
            if (ci < CIN) {
                int mb = mt & 3;
                int sig = (mt >> 2) * 64 + 32 * (mb >> 1) + 8 * (lc >> 2) +
                          4 * (mb & 1) + (lc & 3);
                const float* wr = Wc1 + sig * (CIN * KK) + ci * KK;
                float4 fA = *(const float4*)(wr);
                float4 fB = *(const float4*)(wr + 4);
                v[0] = (_Float16)fA.x; v[1] = (_Float16)fA.y;
                v[2] = (_Float16)fA.z; v[3] = (_Float16)fA.w;
                v[4] = (_Float16)fB.x; v[5] = (_Float16)fB.y;
                v[6] = (_Float16)fB.z; v[7] = (_Float16)fB.w;
            }
            av[s][mt] = v;
        }
    }
    // GEMM2 B-frags direct from Wg: bw[s2][e] = Wg[(s2*32+lg*8+e)*16 + lc]
    half8 bw[2];
#pragma unroll
    for (int s2 = 0; s2 < 2; ++s2) {
        half8 v;
#pragma unroll
        for (int e = 0; e < 8; ++e)
            v[e] = (_Float16)Wg[(s2 * 32 + lg * 8 + e) * H2C + lc];
        bw[s2] = v;
    }

    const float* xr0 = xg + (size_t)lg * WW;
    const float* xr1 = xg + (size_t)(4 + lg) * WW;
    bool cok1 = (4 + lg) < CIN;

    f32x4 acc2[4];
#pragma unroll
    for (int mt2 = 0; mt2 < 4; ++mt2) acc2[mt2] = (f32x4)0.0f;

#pragma unroll
    for (int nt = 0; nt < 4; ++nt) {
        int t = nt * 16 + lc;
        half8 bf0, bf1;
#pragma unroll
        for (int e = 0; e < 8; ++e) {
            int tp = t + e;
            bf0[e] = (_Float16)((tp < WW) ? xr0[tp] : 0.0f);
            bf1[e] = (_Float16)((cok1 && tp < WW) ? xr1[tp] : 0.0f);
        }
        f32x4 acc[8];
#pragma unroll
        for (int mt = 0; mt < 8; ++mt) acc[mt] = (f32x4)0.0f;
#pragma unroll
        for (int mt = 0; mt < 8; ++mt)
            acc[mt] = __builtin_amdgcn_mfma_f32_16x16x32_f16(av[0][mt], bf0,
                                                             acc[mt], 0, 0, 0);
#pragma unroll
        for (int mt = 0; mt < 8; ++mt)
            acc[mt] = __builtin_amdgcn_mfma_f32_16x16x32_f16(av[1][mt], bf1,
                                                             acc[mt], 0, 0, 0);
        half4v h4[4];
#pragma unroll
        for (int mtp = 0; mtp < 4; ++mtp) {
            int cb = 32 * (mtp >> 1) + 8 * lg + 4 * (mtp & 1);
            float4 bP = *(const float4*)(b1 + cb);
            float4 bQ = *(const float4*)(b1 + 64 + cb);
            f32x4 P = acc[mtp];
            f32x4 Q = acc[mtp + 4];
            half4v hh;
            hh[0] = (_Float16)((P[0] + bP.x) * (1.0f / (1.0f + __expf(-(Q[0] + bQ.x)))));
            hh[1] = (_Float16)((P[1] + bP.y) * (1.0f / (1.0f + __expf(-(Q[1] + bQ.y)))));
            hh[2] = (_Float16)((P[2] + bP.z) * (1.0f / (1.0f + __expf(-(Q[2] + bQ.z)))));
            hh[3] = (_Float16)((P[3] + bP.w) * (1.0f / (1.0f + __expf(-(Q[3] + bQ.w)))));
            h4[mtp] = hh;
        }
#pragma unroll
        for (int s2 = 0; s2 < 2; ++s2) {
            half8 af = __builtin_shufflevector(h4[2 * s2], h4[2 * s2 + 1],
                                               0, 1, 2, 3, 4, 5, 6, 7);
            acc2[nt] = __builtin_amdgcn_mfma_f32_16x16x32_f16(af, bw[s2],
                                                              acc2[nt], 0, 0, 0);
        }
    }

    _Float16* xtn = xt + (size_t)n * FT;
#pragma unroll
    for (int mt2 = 0; mt2 < 4; ++mt2) {
#pragma unroll
        for (int j = 0; j < 4; ++j) {
            int t = mt2 * 16 + 4 * lg + j;
            if (t < T1) xtn[t * 16 + lc] = (_Float16)acc2[mt2][j];
        }
    }
}

// ---------------------------------------------------------------------------
// Fused gather + conv2, TWO WAVES PER NODE, ONE NODE PER 128-THREAD BLOCK.
// r13 CONFIRMED the scheduler packs small blocks (Occupancy 36->78%) but
// __launch_bounds__(128,8) capped the allocator at 32 VGPR -> massive scratch
// spill (WRITE 433MB). This round: (128,4) -> 128-VGPR cap, kernel's natural
// ~64-80 fits, LDS 9.2KB still admits 16 blocks/CU = 32 waves.
// Gather loop is the r10-exact form (measured best): 1-deep row pipeline,
// act-masked loads, em/deg prefetched 2-deep with rsqrt off the critical
// chain (r11 depth and r12 ILP probes were both neutral — not the wall).
// gs2 per-node [t][f] 48-B rows (b128 writes, b64 frag reads, k-order in
// w2p). One __syncthreads; each wave does 2 of 4 ntp quadrants; LDS-staged
// coalesced NONTEMPORAL stores (keeps write stream out of L2 -> xt stays
// resident). setprio(1) around the MFMA cluster (independent-wave kernel).
__global__ __launch_bounds__(128, 4) void k_gc2(
        const _Float16* __restrict__ xt, const float* __restrict__ deg,
        const int* __restrict__ cnt, const int2* __restrict__ em,
        const float* __restrict__ bg, const _Float16* __restrict__ w2p,
        const float* __restrict__ b2, float* __restrict__ out) {
    __shared__ __align__(16) _Float16 gs2[58 * GSTR];   // per node, 2784 B
    __shared__ __align__(16) float gout[2][16 * T2];    // per wave, 3200 B
    int tid = threadIdx.x;
    int h = tid >> 6, lane = tid & 63;
    int lc = lane & 15, lg = lane >> 4;
    int n = blockIdx.x;
    bool act = (h == 0) || (lane < 50);
    int idx = (h << 6) + lane;          // half8 index into a node row

    float dc = rsqrtf(deg[n] + 1.0f);
    float a[8];
    {
        const half8* xs = (const half8*)(xt + (size_t)n * FT);
        half8 u = (half8)(_Float16)0.0f;
        if (act) u = xs[idx];
#pragma unroll
        for (int j = 0; j < 8; ++j) a[j] = (float)u[j] * dc;   // self: x*dc
    }
    int beg = n << 6;
    int m = min(cnt[n], CAP);
    int2 rw0 = make_int2(0, 0), rw1 = make_int2(0, 0);
    float dg0 = 0.0f, dg1 = 0.0f;
    half8 c0 = (half8)(_Float16)0.0f;
    if (m > 0) {
        rw0 = em[beg];
        dg0 = deg[rw0.x];
        const half8* xr = (const half8*)(xt + (size_t)rw0.x * FT);
        if (act) c0 = xr[idx];
    }
    if (m > 1) { rw1 = em[beg + 1]; dg1 = deg[rw1.x]; }
    for (int i = 0; i < m; ++i) {
        float wv = __int_as_float(rw0.y) * rsqrtf(dg0 + 1.0f);
        half8 d0 = c0;
        int2 rwn = rw1;
        float dgn = dg1;
        if (i + 2 < m) { rwn = em[beg + i + 2]; dgn = deg[rwn.x]; }
        if (i + 1 < m) {
            const half8* xr = (const half8*)(xt + (size_t)rw1.x * FT);
            c0 = (half8)(_Float16)0.0f;
            if (act) c0 = xr[idx];
        }
        rw0 = rw1; dg0 = dg1; rw1 = rwn; dg1 = dgn;
#pragma unroll
        for (int j = 0; j < 8; ++j) a[j] += (float)d0[j] * wv;
    }

    // relu + bias -> gs2[t][f] (48-B rows). Lane owns t = idx>>1,
    // f = (lane&1)*8 .. +8. One b128 write per active lane.
    // Final feature = dc * (x*dc + sum) + bg, relu.
    {
        _Float16* g = gs2;
        int f0 = (lane & 1) * 8;
        int t0 = idx >> 1;
        float4 bgA = *(const float4*)(bg + f0);
        float4 bgB = *(const float4*)(bg + f0 + 4);
        float bv[8] = {bgA.x, bgA.y, bgA.z, bgA.w, bgB.x, bgB.y, bgB.z, bgB.w};
        half8 h0;
#pragma unroll
        for (int j = 0; j < 8; ++j)
            h0[j] = (_Float16)fmaxf(a[j] * dc + bv[j], 0.0f);
        if (act) *(half8*)(g + t0 * GSTR + f0) = h0;
    }
    __syncthreads();   // both halves' gs2 rows visible to both waves

    const _Float16* g = gs2;
    half8 af[4][4];
#pragma unroll
    for (int s = 0; s < 4; ++s)
#pragma unroll
        for (int mt = 0; mt < 4; ++mt) {
            int tb = mt * 16 + lc + 2 * s;
            half4v lo = *(const half4v*)(g + tb * GSTR + lg * 4);
            half4v hh = *(const half4v*)(g + (tb + 1) * GSTR + lg * 4);
            af[s][mt] = __builtin_shufflevector(lo, hh, 0, 1, 2, 3, 4, 5, 6, 7);
        }

    const half8* wsv = (const half8*)w2p;
    float* outn = out + (size_t)n * (H1C * T2);
    float* go = gout[h];
#pragma unroll
    for (int np2 = 0; np2 < 2; ++np2) {
        int ntp = (h << 1) + np2;
        f32x4 aP[4], aQ[4];
#pragma unroll
        for (int mt = 0; mt < 4; ++mt) { aP[mt] = (f32x4)0.0f; aQ[mt] = (f32x4)0.0f; }
        __builtin_amdgcn_s_setprio(1);
#pragma unroll
        for (int s = 0; s < 4; ++s) {
            half8 bP = wsv[(s * 4 + lg) * 128 + ntp * 16 + lc];
            half8 bQ = wsv[(s * 4 + lg) * 128 + (ntp + 4) * 16 + lc];
#pragma unroll
            for (int mt = 0; mt < 4; ++mt) {
                aP[mt] = __builtin_amdgcn_mfma_f32_16x16x32_f16(af[s][mt], bP,
                                                                aP[mt], 0, 0, 0);
                aQ[mt] = __builtin_amdgcn_mfma_f32_16x16x32_f16(af[s][mt], bQ,
                                                                aQ[mt], 0, 0, 0);
            }
        }
        __builtin_amdgcn_s_setprio(0);
        int c = ntp * 16 + lc;
        float bp = b2[c], bq = b2[64 + c];
        // stage [lc][t<50] into wave-private LDS (column-major rows of 50)
#pragma unroll
        for (int mt = 0; mt < 4; ++mt) {
#pragma unroll
            for (int e2 = 0; e2 < 4; ++e2) {
                int t = mt * 16 + lg * 4 + e2;
                if (t < T2) {
                    float vv = (aP[mt][e2] + bp) *
                               (1.0f / (1.0f + __expf(-(aQ[mt][e2] + bq))));
                    go[lc * T2 + t] = vv;
                }
            }
        }
        // coalesced nontemporal writeback: 800 floats = 3x1024B + 128B
        float* dst = outn + ntp * (16 * T2);
#pragma unroll
        for (int i = 0; i < 3; ++i) {
            f32x4 v = *(const f32x4*)(go + i * 256 + lane * 4);
            __builtin_nontemporal_store(v, (f32x4*)(dst + i * 256 + lane * 4));
        }
        if (lane < 8) {
            f32x4 v = *(const f32x4*)(go + 768 + lane * 4);
            __builtin_nontemporal_store(v, (f32x4*)(dst + 768 + lane * 4));
        }
    }
}

// ---------------------------------------------------------------------------
extern "C" void kernel_launch(void* const* d_in, const int* in_sizes, int n_in,
                              void* d_out, int out_size, void* d_ws, size_t ws_size,
                              hipStream_t stream) {
    const float* x   = (const float*)d_in[0];
    const int*   ei  = (const int*)d_in[1];
    const float* ea  = (const float*)d_in[2];
    const float* Wc1 = (const float*)d_in[4];
    const float* b1  = (const float*)d_in[5];
    const float* Wg  = (const float*)d_in[6];
    const float* bg  = (const float*)d_in[7];
    const float* Wc2 = (const float*)d_in[8];
    const float* b2  = (const float*)d_in[9];
    float* out = (float*)d_out;

    char* ws = (char*)d_ws;
    size_t off = 0;
    auto alloc = [&](size_t bytes) -> void* {
        void* p = ws + off;
        off += (bytes + 255) & ~(size_t)255;
        return p;
    };
    // deg | cnt contiguous -> k_init zeroes both as one 2*NN word range
    float*    deg = (float*)alloc((size_t)NN * 4);      // 31744
    int*      cnt = (int*)alloc((size_t)NN * 4);        // 31744
    int2*     em  = (int2*)alloc((size_t)NN * CAP * 8); // 4.06 MB fixed-cap
    _Float16* xt  = (_Float16*)alloc((size_t)NN * FT * 2);
    _Float16* w2p = (_Float16*)alloc((size_t)16384 * 2);
    (void)alloc(4096);                  // read-slack guard past xt/w2p
    (void)ws_size; (void)in_sizes; (void)n_in; (void)out_size;

    k_init<<<126, 256, 0, stream>>>(deg, Wc2, w2p);
    k_conv1_fill<<<NN / 4 + EE / 256, 256, 0, stream>>>(x, Wc1, b1, Wg, xt,
                                                        ei, ea, deg, cnt, em);
    k_gc2<<<NN, 128, 0, stream>>>(xt, deg, cnt, em, bg, w2p, b2, out);
}

// Round 15
// 94.659 us; speedup vs baseline: 2.1896x; 1.0820x over previous
//
#include <hip/hip_runtime.h>
#include <hip/hip_bf16.h>

#define NN 7936
#define EE 63488
#define CIN 5
#define WW 64
#define KK 8
#define H1C 64
#define H2C 16
#define T1 57            // 64-8+1
#define T2 50            // 57-8+1
#define FT (T1*H2C)      // 912 elems per node for xt (f16)
#define CAP 64           // fixed bucket capacity (P(deg>=64) ~ 1e-35)
#define GSTR 24          // gs row stride in halves (48 B: 16-B aligned rows)

typedef _Float16 half8 __attribute__((ext_vector_type(8)));
typedef _Float16 half4v __attribute__((ext_vector_type(4)));
typedef float f32x4 __attribute__((ext_vector_type(4)));

// ---------------------------------------------------------------------------
// Per-block int64-layout detection: first wave checks high words of the first
// 32 edge indices, ballot, LDS broadcast. ~32 L2-hot ints per block.
__device__ __forceinline__ int block_flag(const int* __restrict__ ei,
                                          int* sflag) {
    if (threadIdx.x < 64) {
        int bad = (threadIdx.x < 32) ? (ei[2 * threadIdx.x + 1] != 0) : 0;
        unsigned long long b = __ballot(bad);
        if (threadIdx.x == 0) *sflag = (b == 0ULL) ? 1 : 0;
    }
    __syncthreads();
    return *sflag;
}

__device__ __forceinline__ int load_row(const int* ei, int f, int e) {
    return f ? ei[2 * e] : ei[e];
}
__device__ __forceinline__ int load_col(const int* ei, int f, int e) {
    return f ? ei[2 * (EE + e)] : ei[EE + e];
}

// ---------------------------------------------------------------------------
// k_init: blocks 0..61 zero deg|cnt (contiguous 2*NN words, 62*256 = 15872
// exactly); blocks 62..161 do weight prep (25600 threads).
// RESTORED r12 form: direct Wc1/Wg loads in conv1 (r13 "slim" variant) were
// 64 scattered 16B requests/wave per fragment -> conv1_fill 30 -> 67µs.
// Preprocessed w1p/wgp gives one contiguous b128 per fragment.
// w2p k-order: element e of a B-frag is (ci = g*4 + (e&3), tap = 2*s+(e>>2))
// — taps grouped in halves so the gc2 A-frag is a plain concat of two 8-B
// LDS rows. MFMA sums over k, so any A/B-consistent k-permutation is valid.
__global__ void k_init(float* __restrict__ deg,
                       const float* __restrict__ Wc2, _Float16* __restrict__ w2p,
                       const float* __restrict__ Wc1, _Float16* __restrict__ w1p,
                       const float* __restrict__ Wg, _Float16* __restrict__ wgp) {
    int b = blockIdx.x;
    if (b < 62) {
        // deg and cnt are contiguous in ws: zero both as one word range
        ((int*)deg)[b * 256 + threadIdx.x] = 0;
        return;
    }
    int i = (b - 62) * 256 + threadIdx.x;
    if (i < 16384) {
        // conv2 B-frags: slot=(s*4+lg)*128+nt*16+c, elem e
        int e = i & 7;
        int slot = i >> 3;
        int c  = slot & 15;
        int nt = (slot >> 4) & 7;
        int g  = (slot >> 7) & 3;
        int s  = (slot >> 9) & 3;
        int ci = g * 4 + (e & 3);
        w2p[i] = (_Float16)Wc2[(nt * 16 + c) * 128 + ci * 8 + 2 * s + (e >> 2)];
    } else if (i < 16384 + 8192) {
        // conv1 GEMM1 A-frags with sigma channel permutation
        int j = i - 16384;
        int e = j & 7;
        int m = (j >> 3) & 127;
        int slg = j >> 10;              // 0..7 = s*4+lg
        int ci = (slg >> 2) * 4 + (slg & 3);
        int hi = m >> 6;                // 0 = P, 1 = Q
        int mb = m & 63;
        int mt = mb >> 4, r = mb & 15;
        int sig = hi * 64 + 32 * (mt >> 1) + 8 * (r >> 2) + 4 * (mt & 1) + (r & 3);
        w1p[j] = (ci < CIN) ? (_Float16)Wc1[sig * (CIN * KK) + ci * KK + e]
                            : (_Float16)0.0f;
    } else if (i < 16384 + 8192 + 1024) {
        // conv1 GEMM2 B-frags (Wg)
        int j = i - 16384 - 8192;
        int e = j & 7;
        int f = (j >> 3) & 15;
        int slg = j >> 7;               // 0..7
        int c = (slg >> 2) * 32 + (slg & 3) * 8 + e;
        wgp[j] = (_Float16)Wg[c * H2C + f];
    }
}

// ---------------------------------------------------------------------------
// Merged kernel: blocks [0, NN/4) run conv1 (register-resident, wave = node);
// blocks [NN/4, NN/4+EE/256) run the edge bucket-fill into FIXED-CAPACITY
// buckets em[c*64+pos], storing RAW (src, ew) and accumulating deg[c] here
// (the dinv[src] fold lives in gc2's prefetch path).
__global__ __launch_bounds__(256, 3) void k_conv1_fill(
        const float* __restrict__ x, const _Float16* __restrict__ w1p,
        const float* __restrict__ b1, const _Float16* __restrict__ wgp,
        _Float16* __restrict__ xt,
        const int* __restrict__ ei,
        const float* __restrict__ ew, float* __restrict__ deg,
        int* __restrict__ cnt, int2* __restrict__ em) {
    if (blockIdx.x >= NN / 4) {
        // ---- bucket fill: em[c*64+pos] = (src, ew); deg[c] += ew ----
        __shared__ int sflag;
        int f = block_flag(ei, &sflag);
        int e = (blockIdx.x - NN / 4) * 256 + threadIdx.x;
        if (e < EE) {
            int c = load_col(ei, f, e);
            int r = load_row(ei, f, e);
            float wv = ew[e];
            int pos = atomicAdd(&cnt[c], 1);
            atomicAdd(&deg[c], wv);
            if (pos < CAP)
                em[(c << 6) + pos] = make_int2(r, __float_as_int(wv));
        }
        return;
    }
    // ---- conv1, fully register-resident (zero LDS, zero barriers) ----
    int tid = threadIdx.x;
    int w = tid >> 6, lane = tid & 63;
    int lc = lane & 15, lg = lane >> 4;
    int n = blockIdx.x * 4 + w;
    const float* xg = x + (size_t)n * (CIN * WW);

    const half8* w1v = (const half8*)w1p;
    const half8* wgv = (const half8*)wgp;

    half8 av[2][8];
#pragma unroll
    for (int s = 0; s < 2; ++s)
#pragma unroll
        for (int mt = 0; mt < 8; ++mt)
            av[s][mt] = w1v[(s * 4 + lg) * 128 + mt * 16 + lc];
    half8 bw[2];
#pragma unroll
    for (int s2 = 0; s2 < 2; ++s2) bw[s2] = wgv[(s2 * 4 + lg) * 16 + lc];

    const float* xr0 = xg + (size_t)lg * WW;
    const float* xr1 = xg + (size_t)(4 + lg) * WW;
    bool cok1 = (4 + lg) < CIN;

    f32x4 acc2[4];
#pragma unroll
    for (int mt2 = 0; mt2 < 4; ++mt2) acc2[mt2] = (f32x4)0.0f;

#pragma unroll
    for (int nt = 0; nt < 4; ++nt) {
        int t = nt * 16 + lc;
        half8 bf0, bf1;
#pragma unroll
        for (int e = 0; e < 8; ++e) {
            int tp = t + e;
            bf0[e] = (_Float16)((tp < WW) ? xr0[tp] : 0.0f);
            bf1[e] = (_Float16)((cok1 && tp < WW) ? xr1[tp] : 0.0f);
        }
        f32x4 acc[8];
#pragma unroll
        for (int mt = 0; mt < 8; ++mt) acc[mt] = (f32x4)0.0f;
#pragma unroll
        for (int mt = 0; mt < 8; ++mt)
            acc[mt] = __builtin_amdgcn_mfma_f32_16x16x32_f16(av[0][mt], bf0,
                                                             acc[mt], 0, 0, 0);
#pragma unroll
        for (int mt = 0; mt < 8; ++mt)
            acc[mt] = __builtin_amdgcn_mfma_f32_16x16x32_f16(av[1][mt], bf1,
                                                             acc[mt], 0, 0, 0);
        half4v h4[4];
#pragma unroll
        for (int mtp = 0; mtp < 4; ++mtp) {
            int cb = 32 * (mtp >> 1) + 8 * lg + 4 * (mtp & 1);
            float4 bP = *(const float4*)(b1 + cb);
            float4 bQ = *(const float4*)(b1 + 64 + cb);
            f32x4 P = acc[mtp];
            f32x4 Q = acc[mtp + 4];
            half4v hh;
            hh[0] = (_Float16)((P[0] + bP.x) * (1.0f / (1.0f + __expf(-(Q[0] + bQ.x)))));
            hh[1] = (_Float16)((P[1] + bP.y) * (1.0f / (1.0f + __expf(-(Q[1] + bQ.y)))));
            hh[2] = (_Float16)((P[2] + bP.z) * (1.0f / (1.0f + __expf(-(Q[2] + bQ.z)))));
            hh[3] = (_Float16)((P[3] + bP.w) * (1.0f / (1.0f + __expf(-(Q[3] + bQ.w)))));
            h4[mtp] = hh;
        }
#pragma unroll
        for (int s2 = 0; s2 < 2; ++s2) {
            half8 af = __builtin_shufflevector(h4[2 * s2], h4[2 * s2 + 1],
                                               0, 1, 2, 3, 4, 5, 6, 7);
            acc2[nt] = __builtin_amdgcn_mfma_f32_16x16x32_f16(af, bw[s2],
                                                              acc2[nt], 0, 0, 0);
        }
    }

    _Float16* xtn = xt + (size_t)n * FT;
#pragma unroll
    for (int mt2 = 0; mt2 < 4; ++mt2) {
#pragma unroll
        for (int j = 0; j < 4; ++j) {
            int t = mt2 * 16 + 4 * lg + j;
            if (t < T1) xtn[t * 16 + lc] = (_Float16)acc2[mt2][j];
        }
    }
}

// ---------------------------------------------------------------------------
// Fused gather + conv2, TWO WAVES PER NODE, ONE NODE PER 128-THREAD BLOCK
// (r14 proven: occupancy packing from r13's probe without the spill;
// inferred gc2 ~25-30 µs). __launch_bounds__(128,4) -> 128-VGPR cap.
// Gather loop is the r10-exact form: 1-deep row pipeline, act-masked loads,
// em/deg prefetched 2-deep with rsqrt off the critical chain.
// gs2 per-node [t][f] 48-B rows (b128 writes, b64 frag reads, k-order in
// w2p). One __syncthreads; each wave does 2 of 4 ntp quadrants; LDS-staged
// coalesced NONTEMPORAL stores. setprio(1) around the MFMA cluster.
__global__ __launch_bounds__(128, 4) void k_gc2(
        const _Float16* __restrict__ xt, const float* __restrict__ deg,
        const int* __restrict__ cnt, const int2* __restrict__ em,
        const float* __restrict__ bg, const _Float16* __restrict__ w2p,
        const float* __restrict__ b2, float* __restrict__ out) {
    __shared__ __align__(16) _Float16 gs2[58 * GSTR];   // per node, 2784 B
    __shared__ __align__(16) float gout[2][16 * T2];    // per wave, 3200 B
    int tid = threadIdx.x;
    int h = tid >> 6, lane = tid & 63;
    int lc = lane & 15, lg = lane >> 4;
    int n = blockIdx.x;
    bool act = (h == 0) || (lane < 50);
    int idx = (h << 6) + lane;          // half8 index into a node row

    float dc = rsqrtf(deg[n] + 1.0f);
    float a[8];
    {
        const half8* xs = (const half8*)(xt + (size_t)n * FT);
        half8 u = (half8)(_Float16)0.0f;
        if (act) u = xs[idx];
#pragma unroll
        for (int j = 0; j < 8; ++j) a[j] = (float)u[j] * dc;   // self: x*dc
    }
    int beg = n << 6;
    int m = min(cnt[n], CAP);
    int2 rw0 = make_int2(0, 0), rw1 = make_int2(0, 0);
    float dg0 = 0.0f, dg1 = 0.0f;
    half8 c0 = (half8)(_Float16)0.0f;
    if (m > 0) {
        rw0 = em[beg];
        dg0 = deg[rw0.x];
        const half8* xr = (const half8*)(xt + (size_t)rw0.x * FT);
        if (act) c0 = xr[idx];
    }
    if (m > 1) { rw1 = em[beg + 1]; dg1 = deg[rw1.x]; }
    for (int i = 0; i < m; ++i) {
        float wv = __int_as_float(rw0.y) * rsqrtf(dg0 + 1.0f);
        half8 d0 = c0;
        int2 rwn = rw1;
        float dgn = dg1;
        if (i + 2 < m) { rwn = em[beg + i + 2]; dgn = deg[rwn.x]; }
        if (i + 1 < m) {
            const half8* xr = (const half8*)(xt + (size_t)rw1.x * FT);
            c0 = (half8)(_Float16)0.0f;
            if (act) c0 = xr[idx];
        }
        rw0 = rw1; dg0 = dg1; rw1 = rwn; dg1 = dgn;
#pragma unroll
        for (int j = 0; j < 8; ++j) a[j] += (float)d0[j] * wv;
    }

    // relu + bias -> gs2[t][f] (48-B rows). Lane owns t = idx>>1,
    // f = (lane&1)*8 .. +8. One b128 write per active lane.
    // Final feature = dc * (x*dc + sum) + bg, relu.
    {
        _Float16* g = gs2;
        int f0 = (lane & 1) * 8;
        int t0 = idx >> 1;
        float4 bgA = *(const float4*)(bg + f0);
        float4 bgB = *(const float4*)(bg + f0 + 4);
        float bv[8] = {bgA.x, bgA.y, bgA.z, bgA.w, bgB.x, bgB.y, bgB.z, bgB.w};
        half8 h0;
#pragma unroll
        for (int j = 0; j < 8; ++j)
            h0[j] = (_Float16)fmaxf(a[j] * dc + bv[j], 0.0f);
        if (act) *(half8*)(g + t0 * GSTR + f0) = h0;
    }
    __syncthreads();   // both halves' gs2 rows visible to both waves

    const _Float16* g = gs2;
    half8 af[4][4];
#pragma unroll
    for (int s = 0; s < 4; ++s)
#pragma unroll
        for (int mt = 0; mt < 4; ++mt) {
            int tb = mt * 16 + lc + 2 * s;
            half4v lo = *(const half4v*)(g + tb * GSTR + lg * 4);
            half4v hh = *(const half4v*)(g + (tb + 1) * GSTR + lg * 4);
            af[s][mt] = __builtin_shufflevector(lo, hh, 0, 1, 2, 3, 4, 5, 6, 7);
        }

    const half8* wsv = (const half8*)w2p;
    float* outn = out + (size_t)n * (H1C * T2);
    float* go = gout[h];
#pragma unroll
    for (int np2 = 0; np2 < 2; ++np2) {
        int ntp = (h << 1) + np2;
        f32x4 aP[4], aQ[4];
#pragma unroll
        for (int mt = 0; mt < 4; ++mt) { aP[mt] = (f32x4)0.0f; aQ[mt] = (f32x4)0.0f; }
        __builtin_amdgcn_s_setprio(1);
#pragma unroll
        for (int s = 0; s < 4; ++s) {
            half8 bP = wsv[(s * 4 + lg) * 128 + ntp * 16 + lc];
            half8 bQ = wsv[(s * 4 + lg) * 128 + (ntp + 4) * 16 + lc];
#pragma unroll
            for (int mt = 0; mt < 4; ++mt) {
                aP[mt] = __builtin_amdgcn_mfma_f32_16x16x32_f16(af[s][mt], bP,
                                                                aP[mt], 0, 0, 0);
                aQ[mt] = __builtin_amdgcn_mfma_f32_16x16x32_f16(af[s][mt], bQ,
                                                                aQ[mt], 0, 0, 0);
            }
        }
        __builtin_amdgcn_s_setprio(0);
        int c = ntp * 16 + lc;
        float bp = b2[c], bq = b2[64 + c];
        // stage [lc][t<50] into wave-private LDS (column-major rows of 50)
#pragma unroll
        for (int mt = 0; mt < 4; ++mt) {
#pragma unroll
            for (int e2 = 0; e2 < 4; ++e2) {
                int t = mt * 16 + lg * 4 + e2;
                if (t < T2) {
                    float vv = (aP[mt][e2] + bp) *
                               (1.0f / (1.0f + __expf(-(aQ[mt][e2] + bq))));
                    go[lc * T2 + t] = vv;
                }
            }
        }
        // coalesced nontemporal writeback: 800 floats = 3x1024B + 128B
        float* dst = outn + ntp * (16 * T2);
#pragma unroll
        for (int i = 0; i < 3; ++i) {
            f32x4 v = *(const f32x4*)(go + i * 256 + lane * 4);
            __builtin_nontemporal_store(v, (f32x4*)(dst + i * 256 + lane * 4));
        }
        if (lane < 8) {
            f32x4 v = *(const f32x4*)(go + 768 + lane * 4);
            __builtin_nontemporal_store(v, (f32x4*)(dst + 768 + lane * 4));
        }
    }
}

// ---------------------------------------------------------------------------
extern "C" void kernel_launch(void* const* d_in, const int* in_sizes, int n_in,
                              void* d_out, int out_size, void* d_ws, size_t ws_size,
                              hipStream_t stream) {
    const float* x   = (const float*)d_in[0];
    const int*   ei  = (const int*)d_in[1];
    const float* ea  = (const float*)d_in[2];
    const float* Wc1 = (const float*)d_in[4];
    const float* b1  = (const float*)d_in[5];
    const float* Wg  = (const float*)d_in[6];
    const float* bg  = (const float*)d_in[7];
    const float* Wc2 = (const float*)d_in[8];
    const float* b2  = (const float*)d_in[9];
    float* out = (float*)d_out;

    char* ws = (char*)d_ws;
    size_t off = 0;
    auto alloc = [&](size_t bytes) -> void* {
        void* p = ws + off;
        off += (bytes + 255) & ~(size_t)255;
        return p;
    };
    // deg | cnt contiguous -> k_init zeroes both as one 2*NN word range
    float*    deg = (float*)alloc((size_t)NN * 4);      // 31744
    int*      cnt = (int*)alloc((size_t)NN * 4);        // 31744
    int2*     em  = (int2*)alloc((size_t)NN * CAP * 8); // 4.06 MB fixed-cap
    _Float16* xt  = (_Float16*)alloc((size_t)NN * FT * 2);
    _Float16* w2p = (_Float16*)alloc((size_t)16384 * 2);
    _Float16* w1p = (_Float16*)alloc((size_t)8192 * 2);
    _Float16* wgp = (_Float16*)alloc((size_t)1024 * 2);
    (void)alloc(4096);                  // read-slack guard past xt/w2p
    (void)ws_size; (void)in_sizes; (void)n_in; (void)out_size;

    k_init<<<162, 256, 0, stream>>>(deg, Wc2, w2p, Wc1, w1p, Wg, wgp);
    k_conv1_fill<<<NN / 4 + EE / 256, 256, 0, stream>>>(x, w1p, b1, wgp, xt,
                                                        ei, ea, deg, cnt, em);
    k_gc2<<<NN, 128, 0, stream>>>(xt, deg, cnt, em, bg, w2p, b2, out);
}